// Round 9
// baseline (325.829 us; speedup 1.0000x reference)
//
#include <hip/hip_runtime.h>

typedef _Float16 f16;
typedef __attribute__((ext_vector_type(4))) _Float16 f16x4;
typedef __attribute__((ext_vector_type(8))) _Float16 f16x8;
typedef __attribute__((ext_vector_type(4))) float f32x4;

constexpr int BATCH  = 4096;
constexpr int SEQ    = 512;
constexpr int HID    = 64;
constexpr int EMB_N4 = 50257 * 64 / 4;   // 804112 float4 groups in emb
constexpr float LOG2E2 = 2.8853900817779268f;   // 2*log2(e), folded into Wih/Whh/bias

// Only the gfx950-verified K32 f16 shape is used.
#define MFMA_K32(a, b, c) __builtin_amdgcn_mfma_f32_16x16x32_f16(a, b, c, 0, 0, 0)

// ---- Prep (r0-style cheap elementwise): emb f32 -> f16 (RNE); Wih/Whh -> f16
// pre-scaled by 2*log2e; zero BN acc. The r5/r6 GEMM prep cost ~+18us vs this
// and bought nothing (the scan pays MFMA-pipe cycles that are otherwise idle).
__global__ __launch_bounds__(256) void prep_kernel(
    const float4* __restrict__ emb4, const float* __restrict__ Wih,
    const float* __restrict__ Whh, f16x4* __restrict__ emb_f4,
    f16* __restrict__ wih_f, f16* __restrict__ whh_f, float* __restrict__ bn_acc)
{
  int gid = blockIdx.x * 256 + threadIdx.x;
  if (gid < EMB_N4) {
    float4 v = emb4[gid];
    emb_f4[gid] = (f16x4){(f16)v.x, (f16)v.y, (f16)v.z, (f16)v.w};
  } else if (gid < EMB_N4 + 1024) {
    int i0 = (gid - EMB_N4) * 4;
    #pragma unroll
    for (int k = 0; k < 4; ++k) {
      int i = i0 + k;
      wih_f[i] = (f16)(Wih[i] * LOG2E2);
      whh_f[i] = (f16)(Whh[i] * LOG2E2);
    }
  } else if (gid < EMB_N4 + 1024 + 128) {
    bn_acc[gid - (EMB_N4 + 1024)] = 0.f;   // ws is poisoned 0xAA every call
  }
}

// ---- Kernel 1: fused gather + input projection + tanh-RNN scan.
// ONE 64-lane wave per 16-row chain (256 blocks x 64 thr = 1 wave/CU).
// Zero LDS, zero barriers, zero sync stall (r3-measured). Issue-stream cuts
// vs r3 (920 cy/step, trans-dominated at ~16 cy/wave64-trans):
//  * batched reciprocal (r6-HW-validated, clamp kept as run): one v_rcp per
//    4 tanh values via prefix-product recovery. Trans/step 32 -> 20.
//  * scalar-cast pack into the interleaved-kappa B-fragment layout
//    (r5-HW-validated: B-chunk c elem k = h[16*(2c+(k&1)) + 4q + (k>>1)]).
//  * IP software-pipelined one step ahead: step s+1's 8 IP MFMAs (depend
//    only on prefetched e-frags) issue during step s's tanh -> step s's
//    critical path is rec-MFMA(depth 2) + tanh only; MFMA pipe (75% idle)
//    absorbs the IP work. Pure reordering of r3's proven MFMA sequence.
// emb gathers keep the 4-slot rotating register prefetch (distance 4 steps,
// ~2000 cy in flight, covers HBM/L3 latency).
__global__ __launch_bounds__(64, 1) void rnn_scan_kernel(
    const int* __restrict__ xx, const f16* __restrict__ emb,
    const f16* __restrict__ wih, const f16* __restrict__ whh,
    const float* __restrict__ b_ih, const float* __restrict__ b_hh,
    float* __restrict__ hT /* [HID][BATCH] */, float* __restrict__ bn_acc)
{
  const int L = threadIdx.x;       // 0..63
  const int n = L & 15;            // batch col within tile / W row within tile
  const int q = L >> 4;            // k-group
  const int R0 = blockIdx.x << 4;  // first batch row of this chain

  // IP A-frags (natural K): Wi[f][half] elem e = wih[16f+n][32*half+8q+e]
  // rec A-frags (interleaved kappa): Wp[f][c] = {lo0,hi0,lo1,hi1,...} with
  // lo_e = whh[16f+n][32c+4q+e], hi_e = whh[16f+n][32c+16+4q+e].
  f16x8 Wi[4][2], Wp[4][2];
  f32x4 bias[4];
  #pragma unroll
  for (int f = 0; f < 4; ++f) {
    const f16* wi = wih + (16 * f + n) * 64;
    Wi[f][0] = *(const f16x8*)(wi + 8 * q);
    Wi[f][1] = *(const f16x8*)(wi + 32 + 8 * q);
    const f16* wr = whh + (16 * f + n) * 64;
    #pragma unroll
    for (int c = 0; c < 2; ++c) {
      f16x4 lo = *(const f16x4*)(wr + 32 * c + 4 * q);
      f16x4 hi = *(const f16x4*)(wr + 32 * c + 16 + 4 * q);
      Wp[f][c] = __builtin_shufflevector(lo, hi, 0, 4, 1, 5, 2, 6, 3, 7);
    }
    // C-layout: lane 16q+n reg r -> feat 16f+4q+r
    float4 bi = *(const float4*)(b_ih + 16 * f + 4 * q);
    float4 bh = *(const float4*)(b_hh + 16 * f + 4 * q);
    bias[f] = (f32x4){(bi.x + bh.x) * LOG2E2, (bi.y + bh.y) * LOG2E2,
                      (bi.z + bh.z) * LOG2E2, (bi.w + bh.w) * LOG2E2};
  }

  // h state as next-step B-fragments (interleaved): hB01 = tiles {0,1},
  // hB23 = tiles {2,3}. h0 = 0.
  f16x8 hB01 = {0, 0, 0, 0, 0, 0, 0, 0};
  f16x8 hB23 = {0, 0, 0, 0, 0, 0, 0, 0};

  // idx stream: int4 = 4 steps; K1 holds steps 4(t+1)..4(t+1)+3.
  const int4* x4 = (const int4*)(xx + (R0 + n) * SEQ);
  int4 K1 = x4[1];

  // emb prefetch slots: slot u holds step 4t+u's B-fragments (distance 4).
  f16x8 e0[4], e1[4];
  {
    int4 K0 = x4[0];
    const int id0[4] = {K0.x, K0.y, K0.z, K0.w};
    #pragma unroll
    for (int u = 0; u < 4; ++u) {
      const f16* eb = emb + (long)id0[u] * 64 + 8 * q;
      e0[u] = *(const f16x8*)(eb);
      e1[u] = *(const f16x8*)(eb + 32);
    }
  }

  // IP for step 0 (pipelined accumulator: Dip always holds NEXT step's IP).
  f32x4 Dip[4];
  #pragma unroll
  for (int f = 0; f < 4; ++f) {
    Dip[f] = MFMA_K32(Wi[f][0], e0[0], bias[f]);
    Dip[f] = MFMA_K32(Wi[f][1], e1[0], Dip[f]);
  }

  for (int t = 0; t < SEQ / 4; ++t) {
    int4 K2 = x4[(t + 2 < SEQ / 4) ? t + 2 : SEQ / 4 - 1];  // clamped; dup loads harmless
    const int nid[4] = {K1.x, K1.y, K1.z, K1.w};            // idx for steps 4t+4+u
    const bool lastt = (t == SEQ / 4 - 1);

    #pragma unroll
    for (int u = 0; u < 4; ++u) {
      // Step s = 4t+u. Recurrence adds into the pre-computed IP:
      f32x4 D0 = MFMA_K32(Wp[0][0], hB01, Dip[0]);
      f32x4 D1 = MFMA_K32(Wp[1][0], hB01, Dip[1]);
      f32x4 D2 = MFMA_K32(Wp[2][0], hB01, Dip[2]);
      f32x4 D3 = MFMA_K32(Wp[3][0], hB01, Dip[3]);
      D0 = MFMA_K32(Wp[0][1], hB23, D0);
      D1 = MFMA_K32(Wp[1][1], hB23, D1);
      D2 = MFMA_K32(Wp[2][1], hB23, D2);
      D3 = MFMA_K32(Wp[3][1], hB23, D3);

      // IP for step s+1 (slot (u+1)&3 -- at u=3, slot 0 was refilled at u=0
      // of this t and holds step 4(t+1)). Independent of D/hB: fills the
      // MFMA pipe while the VALU runs tanh below.
      {
        const int v = (u + 1) & 3;
        #pragma unroll
        for (int f = 0; f < 4; ++f) {
          Dip[f] = MFMA_K32(Wi[f][0], e0[v], bias[f]);
          Dip[f] = MFMA_K32(Wi[f][1], e1[v], Dip[f]);
        }
      }

      // Refill slot u with step s+4 (stays in flight ~4 steps).
      {
        const f16* eb = emb + (long)nid[u] * 64 + 8 * q;
        e0[u] = *(const f16x8*)(eb);
        e1[u] = *(const f16x8*)(eb + 32);
      }

      // tanh(v) = 1 - 2/(1 + 2^s), s = 2log2e*v (pre-scaled in W/bias).
      // A = 1 + 2^min(s,16); one v_rcp per 4 values via prefix products
      // (r6-HW-validated; tanh at s=16 already rounds to 1.0 in f16).
      float th[4][4];
      #pragma unroll
      for (int f = 0; f < 4; ++f) {
        const f32x4 Df = (f == 0) ? D0 : (f == 1) ? D1 : (f == 2) ? D2 : D3;
        float A0 = __builtin_amdgcn_exp2f(fminf(Df[0], 16.0f)) + 1.0f;
        float A1 = __builtin_amdgcn_exp2f(fminf(Df[1], 16.0f)) + 1.0f;
        float A2 = __builtin_amdgcn_exp2f(fminf(Df[2], 16.0f)) + 1.0f;
        float A3 = __builtin_amdgcn_exp2f(fminf(Df[3], 16.0f)) + 1.0f;
        float t1 = A0 * A1, t2 = t1 * A2, t3 = t2 * A3;
        float rr = __builtin_amdgcn_rcpf(t3);
        float i3 = rr * t2;           // 1/A3
        float s3 = rr * A3;           // 1/(A0 A1 A2)
        float i2 = s3 * t1;           // 1/A2
        float s2 = s3 * A2;           // 1/(A0 A1)
        th[f][0] = fmaf(-2.0f, s2 * A1, 1.0f);
        th[f][1] = fmaf(-2.0f, s2 * A0, 1.0f);
        th[f][2] = fmaf(-2.0f, i2, 1.0f);
        th[f][3] = fmaf(-2.0f, i3, 1.0f);
      }

      // Scalar-cast pack into interleaved-kappa B-fragments (r5-proven):
      // hB01 pair r = {th[0][r], th[1][r]}, hB23 pair r = {th[2][r], th[3][r]}.
      #pragma unroll
      for (int r = 0; r < 4; ++r) {
        hB01[2 * r]     = (f16)th[0][r];
        hB01[2 * r + 1] = (f16)th[1][r];
        hB23[2 * r]     = (f16)th[2][r];
        hB23[2 * r + 1] = (f16)th[3][r];
      }

      if (lastt && u == 3) {   // epilogue: h_n out + BN partial sums
        #pragma unroll
        for (int f = 0; f < 4; ++f) {
          #pragma unroll
          for (int r = 0; r < 4; ++r) {
            float v = th[f][r];
            const int feat = 16 * f + 4 * q + r;
            hT[feat * BATCH + R0 + n] = v;     // coalesced over n
            float s1 = v, s2 = v * v;
            s1 += __shfl_xor(s1, 1, 64);  s2 += __shfl_xor(s2, 1, 64);
            s1 += __shfl_xor(s1, 2, 64);  s2 += __shfl_xor(s2, 2, 64);
            s1 += __shfl_xor(s1, 4, 64);  s2 += __shfl_xor(s2, 4, 64);
            s1 += __shfl_xor(s1, 8, 64);  s2 += __shfl_xor(s2, 8, 64);
            if (n == 0) {
              atomicAdd(bn_acc + feat, s1);
              atomicAdd(bn_acc + 64 + feat, s2);
            }
          }
        }
      }
    }
    K1 = K2;
  }
}

// ---- Kernel 2: BN fold (from accumulated sums) + logits GEMV. fp32 out.
__global__ __launch_bounds__(256) void head_kernel(
    const float* __restrict__ hT, const float* __restrict__ bn_acc,
    const float* __restrict__ gamma, const float* __restrict__ beta,
    const float* __restrict__ Wfc, const float* __restrict__ bfc,
    float* __restrict__ out)
{
  __shared__ float sc[64], sh[64];
  const int tid = threadIdx.x;
  if (tid < 64) {
    float mean = bn_acc[tid] * (1.0f / BATCH);
    float var  = bn_acc[64 + tid] * (1.0f / BATCH) - mean * mean;  // biased
    float inv  = rsqrtf(var + 1e-5f);
    float s    = gamma[tid] * inv;
    sc[tid] = s;
    sh[tid] = beta[tid] - mean * s;
  }
  __syncthreads();
  const int b = blockIdx.x * 256 + tid;
  float acc[5];
  #pragma unroll
  for (int c = 0; c < 5; ++c) acc[c] = bfc[c];
  for (int j = 0; j < HID; ++j) {
    float hv  = hT[j * BATCH + b];                 // coalesced across lanes
    float hat = fmaf(hv, sc[j], sh[j]);
    #pragma unroll
    for (int c = 0; c < 5; ++c) acc[c] = fmaf(hat, Wfc[c * 64 + j], acc[c]);
  }
  #pragma unroll
  for (int c = 0; c < 5; ++c) out[b * 5 + c] = acc[c];
}

extern "C" void kernel_launch(void* const* d_in, const int* in_sizes, int n_in,
                              void* d_out, int out_size, void* d_ws, size_t ws_size,
                              hipStream_t stream)
{
  const int*   x     = (const int*)d_in[0];
  const float* emb   = (const float*)d_in[1];
  const float* W_ih  = (const float*)d_in[2];
  const float* W_hh  = (const float*)d_in[3];
  const float* b_ih  = (const float*)d_in[4];
  const float* b_hh  = (const float*)d_in[5];
  const float* gamma = (const float*)d_in[6];
  const float* beta  = (const float*)d_in[7];
  const float* W_fc  = (const float*)d_in[8];
  const float* b_fc  = (const float*)d_in[9];

  char* ws = (char*)d_ws;
  float* hT     = (float*)ws;                 // [64][4096] fp32, 1 MB
  float* bn_acc = (float*)(ws + 1048576);     // [2][64] fp32 atomics
  f16*   emb_f  = (f16*)(ws + 1049088);       // [50257][64] f16, 6.43 MB
  f16*   wih_f  = (f16*)(ws + 7481984);       // [64][64] f16 (pre-scaled)
  f16*   whh_f  = (f16*)(ws + 7490176);       // [64][64] f16 (pre-scaled)

  const int prep_items = EMB_N4 + 1024 + 128;
  prep_kernel<<<dim3((prep_items + 255) / 256), dim3(256), 0, stream>>>(
      (const float4*)emb, W_ih, W_hh, (f16x4*)emb_f, wih_f, whh_f, bn_acc);
  rnn_scan_kernel<<<dim3(BATCH / 16), dim3(64), 0, stream>>>(
      x, emb_f, wih_f, whh_f, b_ih, b_hh, hT, bn_acc);
  head_kernel<<<dim3(BATCH / 256), dim3(256), 0, stream>>>(
      hT, bn_acc, gamma, beta, W_fc, b_fc, (float*)d_out);
}

// Round 10
// 270.764 us; speedup vs baseline: 1.2034x; 1.2034x over previous
//
#include <hip/hip_runtime.h>

typedef _Float16 f16;
typedef __attribute__((ext_vector_type(4))) _Float16 f16x4;
typedef __attribute__((ext_vector_type(8))) _Float16 f16x8;
typedef __attribute__((ext_vector_type(4))) float f32x4;

constexpr int BATCH  = 4096;
constexpr int SEQ    = 512;
constexpr int HID    = 64;
constexpr int EMB_N4 = 50257 * 64 / 4;   // 804112 float4 groups in emb
constexpr float LOG2E2 = 2.8853900817779268f;   // 2*log2(e), folded into Wih/Whh/bias

// Only the gfx950-verified K32 f16 shape is used.
#define MFMA_K32(a, b, c) __builtin_amdgcn_mfma_f32_16x16x32_f16(a, b, c, 0, 0, 0)

// ---- Prep (cheap elementwise, r3-proven): emb f32 -> f16 (RNE); Wih/Whh ->
// f16 pre-scaled by 2*log2e; zero BN acc.
__global__ __launch_bounds__(256) void prep_kernel(
    const float4* __restrict__ emb4, const float* __restrict__ Wih,
    const float* __restrict__ Whh, f16x4* __restrict__ emb_f4,
    f16* __restrict__ wih_f, f16* __restrict__ whh_f, float* __restrict__ bn_acc)
{
  int gid = blockIdx.x * 256 + threadIdx.x;
  if (gid < EMB_N4) {
    float4 v = emb4[gid];
    emb_f4[gid] = (f16x4){(f16)v.x, (f16)v.y, (f16)v.z, (f16)v.w};
  } else if (gid < EMB_N4 + 1024) {
    int i0 = (gid - EMB_N4) * 4;
    #pragma unroll
    for (int k = 0; k < 4; ++k) {
      int i = i0 + k;
      wih_f[i] = (f16)(Wih[i] * LOG2E2);
      whh_f[i] = (f16)(Whh[i] * LOG2E2);
    }
  } else if (gid < EMB_N4 + 1024 + 128) {
    bn_acc[gid - (EMB_N4 + 1024)] = 0.f;   // ws is poisoned 0xAA every call
  }
}

// ---- Kernel 1: producer/consumer tanh-RNN scan. 256 blocks x 128 thr.
// Wave B (producer): embedding gather + input-projection MFMAs, running one
//   4-step iteration AHEAD; writes f32 pre-activations to double-buffered LDS.
// Wave A (consumer): h-recurrence + tanh + pack. h NEVER leaves wave A's
//   registers (r3/r5-proven interleaved-kappa layout: B-chunk c elem k =
//   h[16*(2c+(k&1)) + 4q + (k>>1)]; own D output IS the next B-fragment).
// The IP handoff is NOT on the h-critical path (Dip(s) independent of h), so
// unlike r4/r6's split there is no per-step exchange: ONE lgkmcnt-only
// barrier per 4 steps rotates the LDS parity (~25 cy/step sync).
// Issue budget/step: A = 4 ds_read + 8 MFMA + 16x(exp2,add,rcp,fma) + 16 cvt
// ~ 320 cy; B = 8 loads + 8 MFMA + 4 ds_write + addr ~ 230 cy -> A-bound.
// (r9 lesson: trans are ~4cy issue -> plain per-value tanh beats batched-rcp
// on both issue count and ILP.)
__global__ __launch_bounds__(128, 1) void rnn_scan_kernel(
    const int* __restrict__ xx, const f16* __restrict__ emb,
    const f16* __restrict__ wih, const f16* __restrict__ whh,
    const float* __restrict__ b_ih, const float* __restrict__ b_hh,
    float* __restrict__ hT /* [HID][BATCH] */, float* __restrict__ bn_acc)
{
  __shared__ float4 dipS[2][4][4][64];   // [parity][u][f-tile][lane], 32 KB
  const int tid = threadIdx.x;
  const int w = tid >> 6;          // 0 = consumer A, 1 = producer B
  const int L = tid & 63;
  const int n = L & 15;            // batch col within tile / W row within tile
  const int q = L >> 4;            // k-group
  const int R0 = blockIdx.x << 4;  // first batch row of this chain
  constexpr int NT = SEQ / 4;

  // ---- per-wave state (initialized under divergent guards; each wave only
  // touches its own set) ----
  f16x8 Wi[4][2];  f32x4 bias[4];  f16x8 e0[4], e1[4];   // producer
  f16x8 Wp[4][2];                                         // consumer
  f16x8 hB01 = {0, 0, 0, 0, 0, 0, 0, 0};
  f16x8 hB23 = {0, 0, 0, 0, 0, 0, 0, 0};
  const int4* x4 = (const int4*)(xx + (R0 + n) * SEQ);

  if (w == 1) {
    // Producer init: IP A-frags (natural K, r3-proven) + folded bias.
    #pragma unroll
    for (int f = 0; f < 4; ++f) {
      const f16* wi = wih + (16 * f + n) * 64;
      Wi[f][0] = *(const f16x8*)(wi + 8 * q);
      Wi[f][1] = *(const f16x8*)(wi + 32 + 8 * q);
      float4 bi = *(const float4*)(b_ih + 16 * f + 4 * q);
      float4 bh = *(const float4*)(b_hh + 16 * f + 4 * q);
      bias[f] = (f32x4){(bi.x + bh.x) * LOG2E2, (bi.y + bh.y) * LOG2E2,
                        (bi.z + bh.z) * LOG2E2, (bi.w + bh.w) * LOG2E2};
    }
    // Load e-frags for steps 0..3; compute their IP; publish to parity 0.
    {
      int4 K0 = x4[0];
      const int id0[4] = {K0.x, K0.y, K0.z, K0.w};
      #pragma unroll
      for (int u = 0; u < 4; ++u) {
        const f16* eb = emb + (long)id0[u] * 64 + 8 * q;
        e0[u] = *(const f16x8*)(eb);
        e1[u] = *(const f16x8*)(eb + 32);
      }
      #pragma unroll
      for (int u = 0; u < 4; ++u) {
        #pragma unroll
        for (int f = 0; f < 4; ++f) {
          f32x4 Dp = MFMA_K32(Wi[f][0], e0[u], bias[f]);
          Dp = MFMA_K32(Wi[f][1], e1[u], Dp);
          union { f32x4 v; float4 a; } cv; cv.v = Dp;
          dipS[0][u][f][L] = cv.a;
        }
      }
      // Refill slots with steps 4..7 (consumed in loop iter 0).
      int4 K1 = x4[1];
      const int id1[4] = {K1.x, K1.y, K1.z, K1.w};
      #pragma unroll
      for (int u = 0; u < 4; ++u) {
        const f16* eb = emb + (long)id1[u] * 64 + 8 * q;
        e0[u] = *(const f16x8*)(eb);
        e1[u] = *(const f16x8*)(eb + 32);
      }
    }
  } else {
    // Consumer init: rec A-frags, interleaved kappa (r5-HW-validated):
    // Wp[f][c] = {lo0,hi0,lo1,hi1,...}, lo_e = whh[16f+n][32c+4q+e],
    // hi_e = whh[16f+n][32c+16+4q+e] (whh pre-scaled by LOG2E2).
    #pragma unroll
    for (int f = 0; f < 4; ++f) {
      const f16* wr = whh + (16 * f + n) * 64;
      #pragma unroll
      for (int c = 0; c < 2; ++c) {
        f16x4 lo = *(const f16x4*)(wr + 32 * c + 4 * q);
        f16x4 hi = *(const f16x4*)(wr + 32 * c + 16 + 4 * q);
        Wp[f][c] = __builtin_shufflevector(lo, hi, 0, 4, 1, 5, 2, 6, 3, 7);
      }
    }
  }

  // Parity-0 publish visible; vmcnt untouched (B's refill stays in flight).
  asm volatile("s_waitcnt lgkmcnt(0)\n\ts_barrier" ::: "memory");

  for (int t = 0; t < NT; ++t) {
    if (w == 1) {
      // ---- producer: IP for steps 4(t+1)+u -> parity (t+1)&1; refill
      // slots with steps 4(t+2)+u (one full iteration of load slack).
      if (t + 1 < NT) {
        int4 Kc = x4[(t + 2 < NT) ? t + 2 : NT - 1];   // clamped; dups harmless
        const int nid[4] = {Kc.x, Kc.y, Kc.z, Kc.w};
        const int pw = (t + 1) & 1;
        #pragma unroll
        for (int u = 0; u < 4; ++u) {
          #pragma unroll
          for (int f = 0; f < 4; ++f) {
            f32x4 Dp = MFMA_K32(Wi[f][0], e0[u], bias[f]);
            Dp = MFMA_K32(Wi[f][1], e1[u], Dp);
            union { f32x4 v; float4 a; } cv; cv.v = Dp;
            dipS[pw][u][f][L] = cv.a;
          }
          const f16* eb = emb + (long)nid[u] * 64 + 8 * q;
          e0[u] = *(const f16x8*)(eb);
          e1[u] = *(const f16x8*)(eb + 32);
        }
      }
    } else {
      // ---- consumer: 4 recurrence steps from parity t&1.
      const int p = t & 1;
      union { float4 a; f32x4 v; } Dr[4][4];
      #pragma unroll
      for (int u = 0; u < 4; ++u)
        #pragma unroll
        for (int f = 0; f < 4; ++f)
          Dr[u][f].a = dipS[p][u][f][L];    // all 16 reads issue up front

      const bool lastt = (t == NT - 1);
      #pragma unroll
      for (int u = 0; u < 4; ++u) {
        f32x4 D0 = MFMA_K32(Wp[0][0], hB01, Dr[u][0].v);
        f32x4 D1 = MFMA_K32(Wp[1][0], hB01, Dr[u][1].v);
        f32x4 D2 = MFMA_K32(Wp[2][0], hB01, Dr[u][2].v);
        f32x4 D3 = MFMA_K32(Wp[3][0], hB01, Dr[u][3].v);
        D0 = MFMA_K32(Wp[0][1], hB23, D0);
        D1 = MFMA_K32(Wp[1][1], hB23, D1);
        D2 = MFMA_K32(Wp[2][1], hB23, D2);
        D3 = MFMA_K32(Wp[3][1], hB23, D3);

        // tanh(v) = 1 - 2/(1 + 2^s), s pre-scaled (r3-proven plain form:
        // 16 independent chains, max ILP; trans are ~4cy issue).
        float th[4][4];
        #pragma unroll
        for (int r = 0; r < 4; ++r) {
          float x0 = __builtin_amdgcn_exp2f(D0[r]);
          float x1 = __builtin_amdgcn_exp2f(D1[r]);
          float x2 = __builtin_amdgcn_exp2f(D2[r]);
          float x3 = __builtin_amdgcn_exp2f(D3[r]);
          th[0][r] = fmaf(-2.0f, __builtin_amdgcn_rcpf(x0 + 1.0f), 1.0f);
          th[1][r] = fmaf(-2.0f, __builtin_amdgcn_rcpf(x1 + 1.0f), 1.0f);
          th[2][r] = fmaf(-2.0f, __builtin_amdgcn_rcpf(x2 + 1.0f), 1.0f);
          th[3][r] = fmaf(-2.0f, __builtin_amdgcn_rcpf(x3 + 1.0f), 1.0f);
          // interleaved-kappa pack (r5-proven)
          hB01[2 * r]     = (f16)th[0][r];
          hB01[2 * r + 1] = (f16)th[1][r];
          hB23[2 * r]     = (f16)th[2][r];
          hB23[2 * r + 1] = (f16)th[3][r];
        }

        if (lastt && u == 3) {   // epilogue: h_n out + BN partial sums
          #pragma unroll
          for (int f = 0; f < 4; ++f) {
            #pragma unroll
            for (int r = 0; r < 4; ++r) {
              float v = th[f][r];
              const int feat = 16 * f + 4 * q + r;
              hT[feat * BATCH + R0 + n] = v;     // coalesced over n
              float s1 = v, s2 = v * v;
              s1 += __shfl_xor(s1, 1, 64);  s2 += __shfl_xor(s2, 1, 64);
              s1 += __shfl_xor(s1, 2, 64);  s2 += __shfl_xor(s2, 2, 64);
              s1 += __shfl_xor(s1, 4, 64);  s2 += __shfl_xor(s2, 4, 64);
              s1 += __shfl_xor(s1, 8, 64);  s2 += __shfl_xor(s2, 8, 64);
              if (n == 0) {
                atomicAdd(bn_acc + feat, s1);
                atomicAdd(bn_acc + 64 + feat, s2);
              }
            }
          }
        }
      }
    }
    // LDS-only barrier once per 4 steps: rotates parity. lgkmcnt(0) drains
    // ds ops; vmcnt untouched so B's gather loads live across it.
    asm volatile("s_waitcnt lgkmcnt(0)\n\ts_barrier" ::: "memory");
  }
}

// ---- Kernel 2: BN fold (from accumulated sums) + logits GEMV. fp32 out.
__global__ __launch_bounds__(256) void head_kernel(
    const float* __restrict__ hT, const float* __restrict__ bn_acc,
    const float* __restrict__ gamma, const float* __restrict__ beta,
    const float* __restrict__ Wfc, const float* __restrict__ bfc,
    float* __restrict__ out)
{
  __shared__ float sc[64], sh[64];
  const int tid = threadIdx.x;
  if (tid < 64) {
    float mean = bn_acc[tid] * (1.0f / BATCH);
    float var  = bn_acc[64 + tid] * (1.0f / BATCH) - mean * mean;  // biased
    float inv  = rsqrtf(var + 1e-5f);
    float s    = gamma[tid] * inv;
    sc[tid] = s;
    sh[tid] = beta[tid] - mean * s;
  }
  __syncthreads();
  const int b = blockIdx.x * 256 + tid;
  float acc[5];
  #pragma unroll
  for (int c = 0; c < 5; ++c) acc[c] = bfc[c];
  for (int j = 0; j < HID; ++j) {
    float hv  = hT[j * BATCH + b];                 // coalesced across lanes
    float hat = fmaf(hv, sc[j], sh[j]);
    #pragma unroll
    for (int c = 0; c < 5; ++c) acc[c] = fmaf(hat, Wfc[c * 64 + j], acc[c]);
  }
  #pragma unroll
  for (int c = 0; c < 5; ++c) out[b * 5 + c] = acc[c];
}

extern "C" void kernel_launch(void* const* d_in, const int* in_sizes, int n_in,
                              void* d_out, int out_size, void* d_ws, size_t ws_size,
                              hipStream_t stream)
{
  const int*   x     = (const int*)d_in[0];
  const float* emb   = (const float*)d_in[1];
  const float* W_ih  = (const float*)d_in[2];
  const float* W_hh  = (const float*)d_in[3];
  const float* b_ih  = (const float*)d_in[4];
  const float* b_hh  = (const float*)d_in[5];
  const float* gamma = (const float*)d_in[6];
  const float* beta  = (const float*)d_in[7];
  const float* W_fc  = (const float*)d_in[8];
  const float* b_fc  = (const float*)d_in[9];

  char* ws = (char*)d_ws;
  float* hT     = (float*)ws;                 // [64][4096] fp32, 1 MB
  float* bn_acc = (float*)(ws + 1048576);     // [2][64] fp32 atomics
  f16*   emb_f  = (f16*)(ws + 1049088);       // [50257][64] f16, 6.43 MB
  f16*   wih_f  = (f16*)(ws + 7481984);       // [64][64] f16 (pre-scaled)
  f16*   whh_f  = (f16*)(ws + 7490176);       // [64][64] f16 (pre-scaled)

  const int prep_items = EMB_N4 + 1024 + 128;
  prep_kernel<<<dim3((prep_items + 255) / 256), dim3(256), 0, stream>>>(
      (const float4*)emb, W_ih, W_hh, (f16x4*)emb_f, wih_f, whh_f, bn_acc);
  rnn_scan_kernel<<<dim3(BATCH / 16), dim3(128), 0, stream>>>(
      x, emb_f, wih_f, whh_f, b_ih, b_hh, hT, bn_acc);
  head_kernel<<<dim3(BATCH / 256), dim3(256), 0, stream>>>(
      hT, bn_acc, gamma, beta, W_fc, b_fc, (float*)d_out);
}